// Round 1
// baseline (2520.794 us; speedup 1.0000x reference)
//
#include <hip/hip_runtime.h>
#include <stdint.h>

typedef unsigned long long u64;
typedef unsigned int u32;

#define NA 10647            // total anchors: (52*52 + 26*26 + 13*13) * 3
#define NW 167              // ceil(NA/64) suppression-mask words per row
#define NCLS 20
#define SORT_N 16384
#define OUT_SCORES 42588    // NA*4
#define OUT_CLS    53235    // NA*5
#define OUT_KEEP   63882    // NA*6

// anchors[level][a] * scale{4,2,1}
__constant__ float c_aw[9] = {4.f,8.f,12.f, 3.f,6.f,8.f, 3.5f,5.f,8.f};
__constant__ float c_ah[9] = {6.f,12.f,10.f, 7.f,8.f,6.f, 5.f,4.5f,8.f};

__device__ __forceinline__ float sig(float x){ return 1.0f/(1.0f+expf(-x)); }

__device__ __forceinline__ u64 shfl64(u64 v, int lane){
    int lo = __shfl((int)(u32)(v & 0xffffffffull), lane);
    int hi = __shfl((int)(u32)(v >> 32), lane);
    return ((u64)(u32)hi << 32) | (u32)lo;
}

// ---------------- Phase 1: decode (only batch 0 is used by the reference) ----
__global__ void decode_kernel(const float* __restrict__ p1, const float* __restrict__ p2,
                              const float* __restrict__ p3, float* __restrict__ out,
                              float4* __restrict__ box4, u64* __restrict__ keys,
                              int* __restrict__ clsind, unsigned char* __restrict__ valid)
{
    int n = blockIdx.x*256 + threadIdx.x;
    if (n >= NA) return;
    const float* p; int base, W, HW, L; float s;
    if (n < 8112)      { p=p1; base=0;     W=52; HW=2704; s=8.f;  L=0; }
    else if (n<10140)  { p=p2; base=8112;  W=26; HW=676;  s=16.f; L=1; }
    else               { p=p3; base=10140; W=13; HW=169;  s=32.f; L=2; }
    int r  = n - base;
    int hw = r/3, a = r - hw*3;
    int h  = hw/W, w = hw - h*W;

    // layout: pred[0, ch, h, w] = p[ch*HW + hw];  obj=ch a, cls=ch 3+a*20+c, xywh=ch 63+a*4+j
    float obj = sig(p[(size_t)a*HW + hw]);

    float e[NCLS];
    #pragma unroll
    for (int c=0;c<NCLS;c++) e[c] = p[(size_t)(3 + a*NCLS + c)*HW + hw];
    float xmax = e[0];
    #pragma unroll
    for (int c=1;c<NCLS;c++) xmax = fmaxf(xmax, e[c]);
    float ssum = 0.f;
    #pragma unroll
    for (int c=0;c<NCLS;c++){ e[c] = expf(e[c]-xmax); ssum += e[c]; }
    // mirror ref: all_class = (exp/sum)*obj, argmax first-max, score = max
    float best = -1.0f; int bi = 0;
    #pragma unroll
    for (int c=0;c<NCLS;c++){ float v = (e[c]/ssum)*obj; if (v > best){ best=v; bi=c; } }

    int xb = 63 + a*4;
    float tx = p[(size_t)(xb+0)*HW + hw];
    float ty = p[(size_t)(xb+1)*HW + hw];
    float tw = p[(size_t)(xb+2)*HW + hw];
    float th = p[(size_t)(xb+3)*HW + hw];
    float aw = c_aw[L*3+a], ah = c_ah[L*3+a];
    if (hw == HW-1){ aw=0.f; ah=0.f; }          // ref quirk: awh[hs*ws-1]=0 per level
    float cx = sig(tx) + (float)w;
    float cy = sig(ty) + (float)h;
    float bw = expf(tw)*aw, bh = expf(th)*ah;
    float hx = bw*0.5f,  hy = bh*0.5f;
    float x1 = ((cx-hx)*s)/416.0f;
    float y1 = ((cy-hy)*s)/416.0f;
    float x2 = ((cx+hx)*s)/416.0f;
    float y2 = ((cy+hy)*s)/416.0f;

    out[n*4+0] = fminf(fmaxf(x1*416.0f,0.f),415.f)/416.0f;
    out[n*4+1] = fminf(fmaxf(y1*416.0f,0.f),415.f)/416.0f;
    out[n*4+2] = fminf(fmaxf(x2*416.0f,0.f),415.f)/416.0f;
    out[n*4+3] = fminf(fmaxf(y2*416.0f,0.f),415.f)/416.0f;
    out[OUT_SCORES + n] = best;
    out[OUT_CLS    + n] = (float)bi;

    box4[n]   = make_float4(x1,y1,x2,y2);
    // stable argsort(-scores): ascending by (~score_bits, idx). scores > 0 so bits are monotone.
    keys[n]   = ((u64)(~__float_as_uint(best)) << 32) | (u32)n;
    clsind[n] = bi;
    valid[n]  = (best >= 0.001f) ? 1 : 0;
}

// ---------------- Phase 2: bitonic sort of 16384 u64 keys, split in 8192-halves
__global__ __launch_bounds__(1024) void sort_half(const u64* __restrict__ keysIn,
                                                  u64* __restrict__ keysOut)
{
    __shared__ u64 lk[8192];                    // exactly 64 KB
    int b = blockIdx.x, tid = threadIdx.x;
    bool desc = (b == 1);                       // half0 asc, half1 desc -> bitonic 16384
    for (int t=tid;t<8192;t+=1024){ int g=b*8192+t; lk[t] = (g<NA)? keysIn[g] : ~0ull; }
    __syncthreads();
    for (int k=2;k<=8192;k<<=1){
        for (int j=k>>1;j>0;j>>=1){
            for (int t=tid;t<4096;t+=1024){
                int low=t&(j-1); int i=((t^low)<<1)|low; int ix=i|j;
                bool asc = ((i&k)==0) != desc;
                u64 A=lk[i], B=lk[ix];
                if ((A>B)==asc){ lk[i]=B; lk[ix]=A; }
            }
            __syncthreads();
        }
    }
    for (int t=tid;t<8192;t+=1024) keysOut[b*8192+t]=lk[t];
}

__global__ void merge_step(u64* __restrict__ keys){   // k=16384, j=8192 step, ascending
    int t = blockIdx.x*256 + threadIdx.x;
    if (t < 8192){ u64 A=keys[t], B=keys[t+8192]; if (A>B){ keys[t]=B; keys[t+8192]=A; } }
}

__global__ __launch_bounds__(1024) void sort_final(const u64* __restrict__ keys,
                                                   u32* __restrict__ order)
{
    __shared__ u64 lk[8192];
    int b=blockIdx.x, tid=threadIdx.x;
    for (int t=tid;t<8192;t+=1024) lk[t]=keys[b*8192+t];
    __syncthreads();
    for (int j=4096;j>0;j>>=1){                 // remaining merge steps, all ascending
        for (int t=tid;t<4096;t+=1024){
            int low=t&(j-1); int i=((t^low)<<1)|low; int ix=i|j;
            u64 A=lk[i], B=lk[ix];
            if (A>B){ lk[i]=B; lk[ix]=A; }
        }
        __syncthreads();
    }
    for (int t=tid;t<8192;t+=1024){ int g=b*8192+t; if (g<NA) order[g]=(u32)lk[t]; }
}

// ---------------- Phase 3: gather into sorted SoA ---------------------------
__global__ void gather_kernel(const u32* __restrict__ order, const float4* __restrict__ box4,
                              const int* __restrict__ clsind, const unsigned char* __restrict__ valid,
                              float* __restrict__ sx1, float* __restrict__ sy1,
                              float* __restrict__ sx2, float* __restrict__ sy2,
                              float* __restrict__ sarea, int* __restrict__ scls,
                              unsigned char* __restrict__ sval)
{
    int i = blockIdx.x*256 + threadIdx.x;
    if (i >= NA) return;
    u32 o = order[i];
    float4 b = box4[o];
    sx1[i]=b.x; sy1[i]=b.y; sx2[i]=b.z; sy2[i]=b.w;
    sarea[i] = (b.z-b.x)*(b.w-b.y);
    scls[i]=clsind[o]; sval[i]=valid[o];
}

// ---------------- Phase 4: IoU suppression mask (wave per row, ballot per word)
__global__ void mask_kernel(const float* __restrict__ sx1, const float* __restrict__ sy1,
                            const float* __restrict__ sx2, const float* __restrict__ sy2,
                            const float* __restrict__ sarea, const int* __restrict__ scls,
                            u64* __restrict__ mask)
{
    int wave = (int)((blockIdx.x*(u32)blockDim.x + threadIdx.x) >> 6);
    int lane = threadIdx.x & 63;
    if (wave >= NA) return;
    int i = wave;
    float bx1=sx1[i], by1=sy1[i], bx2=sx2[i], by2=sy2[i], ba=sarea[i];
    int bc = scls[i];
    u64* row = mask + (size_t)i*NW;
    for (int w=0; w<NW; w++){
        int j = w*64 + lane;
        bool pred = false;
        if (j < NA){
            float xx1=fmaxf(bx1,sx1[j]), yy1=fmaxf(by1,sy1[j]);
            float xx2=fminf(bx2,sx2[j]), yy2=fminf(by2,sy2[j]);
            float inter = fmaxf(1e-28f,xx2-xx1)*fmaxf(1e-28f,yy2-yy1);
            float iou = inter/((ba + sarea[j]) - inter);
            pred = (iou > 0.5f) && (scls[j]==bc);
        }
        u64 bm = __ballot(pred);
        if (lane==0) row[w] = bm;
    }
}

// ---------------- Phase 5: sequential NMS scan, single wave ------------------
// removed bitmask lives in registers: lane l holds words {l, l+64, l+128}.
// Per 64-chunk: only each candidate row's diagonal word is serially needed ->
// preload those in parallel, resolve chunk via shuffles, then bulk-OR kept rows
// 4-at-a-time (OR idempotent; remainder slots duplicate b0).
__global__ __launch_bounds__(64) void scan_kernel(const u64* __restrict__ mask,
        const unsigned char* __restrict__ sval, const u32* __restrict__ order,
        float* __restrict__ keep_out)
{
    int lane = threadIdx.x;
    __shared__ u64 vw_s[NW];
    for (int w=0; w<NW; w++){
        int j = w*64 + lane;
        int v = (j<NA) ? sval[j] : 0;
        u64 bm = __ballot(v != 0);
        if (lane==0) vw_s[w] = bm;
    }
    __syncthreads();

    u64 r0=0, r1=0, r2=0;
    for (int cw=0; cw<NW; cw++){
        int slot = cw>>6, owner = cw&63;
        u64 rsel = (slot==0)? r0 : ((slot==1)? r1 : r2);
        u64 rem  = shfl64(rsel, owner);           // wave-uniform removed word for this chunk
        u64 cand = vw_s[cw] & ~rem;
        u64 myword = 0;
        if ((cand >> lane) & 1ull)
            myword = mask[(size_t)(cw*64+lane)*NW + cw];   // diagonal word of candidate row
        u64 keepw = 0;
        while (cand){                              // uniform control flow
            int bp = __builtin_ctzll(cand);
            cand &= cand - 1;
            if (!((rem >> bp) & 1ull)){
                keepw |= (1ull << bp);
                rem |= shfl64(myword, bp);
                cand &= ~rem;
            }
        }
        u64 kw = keepw;                            // bulk OR of kept rows into removed regs
        while (kw){
            int b0 = __builtin_ctzll(kw); kw &= kw-1;
            int b1=b0,b2=b0,b3=b0;
            if (kw){ b1=__builtin_ctzll(kw); kw&=kw-1; }
            if (kw){ b2=__builtin_ctzll(kw); kw&=kw-1; }
            if (kw){ b3=__builtin_ctzll(kw); kw&=kw-1; }
            const u64* R0 = mask + (size_t)(cw*64+b0)*NW;
            const u64* R1 = mask + (size_t)(cw*64+b1)*NW;
            const u64* R2 = mask + (size_t)(cw*64+b2)*NW;
            const u64* R3 = mask + (size_t)(cw*64+b3)*NW;
            u64 a0=R0[lane],    a1=R1[lane],    a2=R2[lane],    a3=R3[lane];
            u64 c0=R0[64+lane], c1=R1[64+lane], c2=R2[64+lane], c3=R3[64+lane];
            u64 d0=0,d1=0,d2=0,d3=0;
            if (lane < NW-128){ d0=R0[128+lane]; d1=R1[128+lane]; d2=R2[128+lane]; d3=R3[128+lane]; }
            r0 |= a0|a1|a2|a3;
            r1 |= c0|c1|c2|c3;
            r2 |= d0|d1|d2|d3;
        }
        int i = cw*64 + lane;
        if (i < NA)
            keep_out[order[i]] = ((keepw>>lane)&1ull) ? 1.0f : 0.0f;
    }
}

// ---------------- launch -----------------------------------------------------
extern "C" void kernel_launch(void* const* d_in, const int* in_sizes, int n_in,
                              void* d_out, int out_size, void* d_ws, size_t ws_size,
                              hipStream_t stream) {
    const float* p1 = (const float*)d_in[0];
    const float* p2 = (const float*)d_in[1];
    const float* p3 = (const float*)d_in[2];
    float* out = (float*)d_out;

    char* ws = (char*)d_ws;
    size_t off = 0;
    auto alloc = [&](size_t bytes)->void*{ void* p = ws + off; off += (bytes + 255) & ~(size_t)255; return p; };
    float4* box4          = (float4*)alloc((size_t)NA*16);
    u64*    keys          = (u64*)   alloc((size_t)SORT_N*8);
    int*    clsind        = (int*)   alloc((size_t)NA*4);
    unsigned char* valid  = (unsigned char*)alloc(NA);
    u32*    order         = (u32*)   alloc((size_t)NA*4);
    float*  sx1           = (float*) alloc((size_t)NA*4);
    float*  sy1           = (float*) alloc((size_t)NA*4);
    float*  sx2           = (float*) alloc((size_t)NA*4);
    float*  sy2           = (float*) alloc((size_t)NA*4);
    float*  sarea         = (float*) alloc((size_t)NA*4);
    int*    scls          = (int*)   alloc((size_t)NA*4);
    unsigned char* sval   = (unsigned char*)alloc(NA);
    u64*    mask          = (u64*)   alloc((size_t)NA*NW*8);   // ~14.2 MB

    decode_kernel<<<(NA+255)/256, 256, 0, stream>>>(p1,p2,p3,out,box4,keys,clsind,valid);
    sort_half   <<<2, 1024, 0, stream>>>(keys, keys);
    merge_step  <<<32, 256, 0, stream>>>(keys);
    sort_final  <<<2, 1024, 0, stream>>>(keys, order);
    gather_kernel<<<(NA+255)/256, 256, 0, stream>>>(order, box4, clsind, valid,
                                                    sx1,sy1,sx2,sy2,sarea,scls,sval);
    mask_kernel <<<(NA+3)/4, 256, 0, stream>>>(sx1,sy1,sx2,sy2,sarea,scls,mask);
    scan_kernel <<<1, 64, 0, stream>>>(mask, sval, order, out + OUT_KEEP);
}

// Round 2
// 2230.540 us; speedup vs baseline: 1.1301x; 1.1301x over previous
//
#include <hip/hip_runtime.h>
#include <stdint.h>

typedef unsigned long long u64;
typedef unsigned int u32;

#define NA 10647            // total anchors: (52*52 + 26*26 + 13*13) * 3
#define NW 167              // ceil(NA/64) suppression-mask words per row
#define NCLS 20
#define SORT_N 16384
#define OUT_SCORES 42588    // NA*4
#define OUT_CLS    53235    // NA*5
#define OUT_KEEP   63882    // NA*6

// anchors[level][a] * scale{4,2,1}
__constant__ float c_aw[9] = {4.f,8.f,12.f, 3.f,6.f,8.f, 3.5f,5.f,8.f};
__constant__ float c_ah[9] = {6.f,12.f,10.f, 7.f,8.f,6.f, 5.f,4.5f,8.f};

__device__ __forceinline__ float sig(float x){ return 1.0f/(1.0f+expf(-x)); }

__device__ __forceinline__ u64 shfl64(u64 v, int lane){
    int lo = __shfl((int)(u32)(v & 0xffffffffull), lane);
    int hi = __shfl((int)(u32)(v >> 32), lane);
    return ((u64)(u32)hi << 32) | (u32)lo;
}

// ---------------- Phase 1: decode (only batch 0 is used by the reference) ----
__global__ void decode_kernel(const float* __restrict__ p1, const float* __restrict__ p2,
                              const float* __restrict__ p3, float* __restrict__ out,
                              float4* __restrict__ box4, u64* __restrict__ keys,
                              int* __restrict__ clsind, unsigned char* __restrict__ valid)
{
    int n = blockIdx.x*256 + threadIdx.x;
    if (n >= NA) return;
    const float* p; int base, W, HW, L; float s;
    if (n < 8112)      { p=p1; base=0;     W=52; HW=2704; s=8.f;  L=0; }
    else if (n<10140)  { p=p2; base=8112;  W=26; HW=676;  s=16.f; L=1; }
    else               { p=p3; base=10140; W=13; HW=169;  s=32.f; L=2; }
    int r  = n - base;
    int hw = r/3, a = r - hw*3;
    int h  = hw/W, w = hw - h*W;

    // layout: pred[0, ch, h, w] = p[ch*HW + hw];  obj=ch a, cls=ch 3+a*20+c, xywh=ch 63+a*4+j
    float obj = sig(p[(size_t)a*HW + hw]);

    float e[NCLS];
    #pragma unroll
    for (int c=0;c<NCLS;c++) e[c] = p[(size_t)(3 + a*NCLS + c)*HW + hw];
    float xmax = e[0];
    #pragma unroll
    for (int c=1;c<NCLS;c++) xmax = fmaxf(xmax, e[c]);
    float ssum = 0.f;
    #pragma unroll
    for (int c=0;c<NCLS;c++){ e[c] = expf(e[c]-xmax); ssum += e[c]; }
    // mirror ref: all_class = (exp/sum)*obj, argmax first-max, score = max
    float best = -1.0f; int bi = 0;
    #pragma unroll
    for (int c=0;c<NCLS;c++){ float v = (e[c]/ssum)*obj; if (v > best){ best=v; bi=c; } }

    int xb = 63 + a*4;
    float tx = p[(size_t)(xb+0)*HW + hw];
    float ty = p[(size_t)(xb+1)*HW + hw];
    float tw = p[(size_t)(xb+2)*HW + hw];
    float th = p[(size_t)(xb+3)*HW + hw];
    float aw = c_aw[L*3+a], ah = c_ah[L*3+a];
    if (hw == HW-1){ aw=0.f; ah=0.f; }          // ref quirk: awh[hs*ws-1]=0 per level
    float cx = sig(tx) + (float)w;
    float cy = sig(ty) + (float)h;
    float bw = expf(tw)*aw, bh = expf(th)*ah;
    float hx = bw*0.5f,  hy = bh*0.5f;
    float x1 = ((cx-hx)*s)/416.0f;
    float y1 = ((cy-hy)*s)/416.0f;
    float x2 = ((cx+hx)*s)/416.0f;
    float y2 = ((cy+hy)*s)/416.0f;

    out[n*4+0] = fminf(fmaxf(x1*416.0f,0.f),415.f)/416.0f;
    out[n*4+1] = fminf(fmaxf(y1*416.0f,0.f),415.f)/416.0f;
    out[n*4+2] = fminf(fmaxf(x2*416.0f,0.f),415.f)/416.0f;
    out[n*4+3] = fminf(fmaxf(y2*416.0f,0.f),415.f)/416.0f;
    out[OUT_SCORES + n] = best;
    out[OUT_CLS    + n] = (float)bi;

    box4[n]   = make_float4(x1,y1,x2,y2);
    // stable argsort(-scores): ascending by (~score_bits, idx). scores > 0 so bits are monotone.
    keys[n]   = ((u64)(~__float_as_uint(best)) << 32) | (u32)n;
    clsind[n] = bi;
    valid[n]  = (best >= 0.001f) ? 1 : 0;
}

// ---------------- Phase 2: bitonic sort of 16384 u64 keys, split in 8192-halves
__global__ __launch_bounds__(1024) void sort_half(const u64* __restrict__ keysIn,
                                                  u64* __restrict__ keysOut)
{
    __shared__ u64 lk[8192];                    // exactly 64 KB
    int b = blockIdx.x, tid = threadIdx.x;
    bool desc = (b == 1);                       // half0 asc, half1 desc -> bitonic 16384
    for (int t=tid;t<8192;t+=1024){ int g=b*8192+t; lk[t] = (g<NA)? keysIn[g] : ~0ull; }
    __syncthreads();
    for (int k=2;k<=8192;k<<=1){
        for (int j=k>>1;j>0;j>>=1){
            for (int t=tid;t<4096;t+=1024){
                int low=t&(j-1); int i=((t^low)<<1)|low; int ix=i|j;
                bool asc = ((i&k)==0) != desc;
                u64 A=lk[i], B=lk[ix];
                if ((A>B)==asc){ lk[i]=B; lk[ix]=A; }
            }
            __syncthreads();
        }
    }
    for (int t=tid;t<8192;t+=1024) keysOut[b*8192+t]=lk[t];
}

__global__ void merge_step(u64* __restrict__ keys){   // k=16384, j=8192 step, ascending
    int t = blockIdx.x*256 + threadIdx.x;
    if (t < 8192){ u64 A=keys[t], B=keys[t+8192]; if (A>B){ keys[t]=B; keys[t+8192]=A; } }
}

__global__ __launch_bounds__(1024) void sort_final(const u64* __restrict__ keys,
                                                   u32* __restrict__ order)
{
    __shared__ u64 lk[8192];
    int b=blockIdx.x, tid=threadIdx.x;
    for (int t=tid;t<8192;t+=1024) lk[t]=keys[b*8192+t];
    __syncthreads();
    for (int j=4096;j>0;j>>=1){                 // remaining merge steps, all ascending
        for (int t=tid;t<4096;t+=1024){
            int low=t&(j-1); int i=((t^low)<<1)|low; int ix=i|j;
            u64 A=lk[i], B=lk[ix];
            if (A>B){ lk[i]=B; lk[ix]=A; }
        }
        __syncthreads();
    }
    for (int t=tid;t<8192;t+=1024){ int g=b*8192+t; if (g<NA) order[g]=(u32)lk[t]; }
}

// ---------------- Phase 3: gather into sorted arrays (packed) ---------------
__global__ void gather_kernel(const u32* __restrict__ order, const float4* __restrict__ box4,
                              const int* __restrict__ clsind, const unsigned char* __restrict__ valid,
                              float4* __restrict__ sbox, float* __restrict__ sarea,
                              int* __restrict__ scls, unsigned char* __restrict__ sval)
{
    int i = blockIdx.x*256 + threadIdx.x;
    if (i >= NA) return;
    u32 o = order[i];
    float4 b = box4[o];
    sbox[i] = b;
    sarea[i] = (b.z-b.x)*(b.w-b.y);
    scls[i]=clsind[o]; sval[i]=valid[o];
}

// ---------------- Phase 4: IoU suppression mask ------------------------------
// 16 rows per 1024-thread block; columns staged through LDS in 256-wide tiles.
__global__ __launch_bounds__(1024) void mask_kernel(const float4* __restrict__ sbox,
                                                    const float* __restrict__ sarea,
                                                    const int* __restrict__ scls,
                                                    u64* __restrict__ mask)
{
    __shared__ float4 tb[256];
    __shared__ float  ta[256];
    __shared__ int    tc[256];
    int wave = threadIdx.x >> 6, lane = threadIdx.x & 63;
    int row  = blockIdx.x*16 + wave;
    bool rowok = row < NA;
    float4 b = make_float4(0,0,0,0); float ba = 0.f; int bc = -1;
    if (rowok){ b = sbox[row]; ba = sarea[row]; bc = scls[row]; }
    for (int t0 = 0; t0 < NA; t0 += 256){
        __syncthreads();
        int j = t0 + threadIdx.x;
        if (threadIdx.x < 256 && j < NA){
            tb[threadIdx.x] = sbox[j];
            ta[threadIdx.x] = sarea[j];
            tc[threadIdx.x] = scls[j];
        }
        __syncthreads();
        if (rowok){
            #pragma unroll
            for (int sub = 0; sub < 4; sub++){
                int jj = sub*64 + lane;
                int gj = t0 + jj;
                bool pred = false;
                if (gj < NA){
                    float4 c = tb[jj];
                    float xx1=fmaxf(b.x,c.x), yy1=fmaxf(b.y,c.y);
                    float xx2=fminf(b.z,c.z), yy2=fminf(b.w,c.w);
                    float inter = fmaxf(1e-28f,xx2-xx1)*fmaxf(1e-28f,yy2-yy1);
                    float iou = inter/((ba + ta[jj]) - inter);
                    pred = (iou > 0.5f) && (tc[jj]==bc);
                }
                u64 bm = __ballot(pred);
                int wi = (t0>>6) + sub;
                if (lane==0 && wi < NW) mask[(size_t)row*NW + wi] = bm;
            }
        }
    }
}

// ---------------- Phase 5: sequential NMS scan, 16 waves ---------------------
// Wave 0 resolves each 64-candidate chunk serially (shuffles only). All 16
// waves then cooperatively OR the kept rows' FORWARD words (w > cw) into an
// LDS removed-accumulator via ds_or atomics. Diagonal words for the next
// chunk are double-buffer prefetched during the OR phase.
__global__ __launch_bounds__(1024) void scan_kernel(const u64* __restrict__ mask,
        const unsigned char* __restrict__ sval, const u32* __restrict__ order,
        float* __restrict__ keep_out)
{
    __shared__ u64 vw_s[NW];
    __shared__ u32 rem_lo[NW], rem_hi[NW];
    __shared__ u64 diag[2][64];
    __shared__ u64 keep_s;
    int tid = threadIdx.x;
    int wave = tid >> 6, lane = tid & 63;

    for (int w = tid; w < NW; w += 1024){ rem_lo[w] = 0u; rem_hi[w] = 0u; }
    if (wave == 0){
        for (int w = 0; w < NW; w++){
            int j = w*64 + lane;
            u64 bm = __ballot(j < NA && sval[j]);
            if (lane == 0) vw_s[w] = bm;
        }
    }
    if (wave == 1){
        diag[0][lane] = mask[(size_t)lane*NW + 0];   // rows 0..63, word 0
    }
    __syncthreads();

    for (int cw = 0; cw < NW; cw++){
        // ---- resolve chunk cw (wave 0 only) ----
        if (wave == 0){
            u64 rem = ((u64)rem_hi[cw] << 32) | rem_lo[cw];
            u64 cand = vw_s[cw] & ~rem;
            u64 myword = diag[cw & 1][lane];
            u64 keepw = 0;
            while (cand){
                int bp = __builtin_ctzll(cand); cand &= cand - 1;
                if (!((rem >> bp) & 1ull)){
                    keepw |= 1ull << bp;
                    rem |= shfl64(myword, bp);
                    cand &= ~rem;
                }
            }
            if (lane == 0) keep_s = keepw;
        }
        __syncthreads();
        u64 keepw = keep_s;

        // ---- prefetch next chunk's diagonal words (wave 1) ----
        if (wave == 1 && cw + 1 < NW){
            int r = (cw+1)*64 + lane;
            diag[(cw+1) & 1][lane] = (r < NA) ? mask[(size_t)r*NW + (cw+1)] : 0ull;
        }

        // ---- write keep bits for this chunk (wave 2) ----
        if (wave == 2){
            int i = cw*64 + lane;
            if (i < NA)
                keep_out[order[i]] = ((keepw >> lane) & 1ull) ? 1.0f : 0.0f;
        }

        // ---- all waves: OR forward words of kept rows into LDS rem ----
        {
            u64 kw = keepw;
            int kidx = 0;
            while (kw){
                int bp = __builtin_ctzll(kw); kw &= kw - 1;
                if ((kidx & 15) == wave){
                    const u64* R = mask + (size_t)(cw*64 + bp)*NW;
                    for (int w = cw + 1 + lane; w < NW; w += 64){
                        u64 v = R[w];
                        if (v){
                            atomicOr(&rem_lo[w], (u32)v);
                            atomicOr(&rem_hi[w], (u32)(v >> 32));
                        }
                    }
                }
                kidx++;
            }
        }
        __syncthreads();
    }
}

// ---------------- launch -----------------------------------------------------
extern "C" void kernel_launch(void* const* d_in, const int* in_sizes, int n_in,
                              void* d_out, int out_size, void* d_ws, size_t ws_size,
                              hipStream_t stream) {
    const float* p1 = (const float*)d_in[0];
    const float* p2 = (const float*)d_in[1];
    const float* p3 = (const float*)d_in[2];
    float* out = (float*)d_out;

    char* ws = (char*)d_ws;
    size_t off = 0;
    auto alloc = [&](size_t bytes)->void*{ void* p = ws + off; off += (bytes + 255) & ~(size_t)255; return p; };
    float4* box4          = (float4*)alloc((size_t)NA*16);
    u64*    keys          = (u64*)   alloc((size_t)SORT_N*8);
    int*    clsind        = (int*)   alloc((size_t)NA*4);
    unsigned char* valid  = (unsigned char*)alloc(NA);
    u32*    order         = (u32*)   alloc((size_t)NA*4);
    float4* sbox          = (float4*)alloc((size_t)NA*16);
    float*  sarea         = (float*) alloc((size_t)NA*4);
    int*    scls          = (int*)   alloc((size_t)NA*4);
    unsigned char* sval   = (unsigned char*)alloc(NA);
    u64*    mask          = (u64*)   alloc((size_t)NA*NW*8);   // ~14.2 MB

    decode_kernel<<<(NA+255)/256, 256, 0, stream>>>(p1,p2,p3,out,box4,keys,clsind,valid);
    sort_half   <<<2, 1024, 0, stream>>>(keys, keys);
    merge_step  <<<32, 256, 0, stream>>>(keys);
    sort_final  <<<2, 1024, 0, stream>>>(keys, order);
    gather_kernel<<<(NA+255)/256, 256, 0, stream>>>(order, box4, clsind, valid,
                                                    sbox, sarea, scls, sval);
    mask_kernel <<<(NA+15)/16, 1024, 0, stream>>>(sbox, sarea, scls, mask);
    scan_kernel <<<1, 1024, 0, stream>>>(mask, sval, order, out + OUT_KEEP);
}

// Round 3
// 484.232 us; speedup vs baseline: 5.2058x; 4.6063x over previous
//
#include <hip/hip_runtime.h>
#include <stdint.h>

typedef unsigned long long u64;
typedef unsigned int u32;

#define NA 10647            // total anchors: (52*52 + 26*26 + 13*13) * 3
#define NCLS 20
#define SORT_N 16384
#define CAP 2048            // per-class capacity (mean 532, 60+ sigma headroom)
#define OUT_SCORES 42588    // NA*4
#define OUT_CLS    53235    // NA*5
#define OUT_KEEP   63882    // NA*6

// anchors[level][a] * scale{4,2,1}
__constant__ float c_aw[9] = {4.f,8.f,12.f, 3.f,6.f,8.f, 3.5f,5.f,8.f};
__constant__ float c_ah[9] = {6.f,12.f,10.f, 7.f,8.f,6.f, 5.f,4.5f,8.f};

__device__ __forceinline__ float sig(float x){ return 1.0f/(1.0f+expf(-x)); }

// ---------------- Phase 1: decode (only batch 0 is used by the reference) ----
__global__ void decode_kernel(const float* __restrict__ p1, const float* __restrict__ p2,
                              const float* __restrict__ p3, float* __restrict__ out,
                              float4* __restrict__ box4, u64* __restrict__ keys,
                              int* __restrict__ clsind, unsigned char* __restrict__ valid)
{
    int n = blockIdx.x*256 + threadIdx.x;
    if (n >= NA) return;
    const float* p; int base, W, HW, L; float s;
    if (n < 8112)      { p=p1; base=0;     W=52; HW=2704; s=8.f;  L=0; }
    else if (n<10140)  { p=p2; base=8112;  W=26; HW=676;  s=16.f; L=1; }
    else               { p=p3; base=10140; W=13; HW=169;  s=32.f; L=2; }
    int r  = n - base;
    int hw = r/3, a = r - hw*3;
    int h  = hw/W, w = hw - h*W;

    // layout: pred[0, ch, h, w] = p[ch*HW + hw];  obj=ch a, cls=ch 3+a*20+c, xywh=ch 63+a*4+j
    float obj = sig(p[(size_t)a*HW + hw]);

    float e[NCLS];
    #pragma unroll
    for (int c=0;c<NCLS;c++) e[c] = p[(size_t)(3 + a*NCLS + c)*HW + hw];
    float xmax = e[0];
    #pragma unroll
    for (int c=1;c<NCLS;c++) xmax = fmaxf(xmax, e[c]);
    float ssum = 0.f;
    #pragma unroll
    for (int c=0;c<NCLS;c++){ e[c] = expf(e[c]-xmax); ssum += e[c]; }
    // mirror ref: all_class = (exp/sum)*obj, argmax first-max, score = max
    float best = -1.0f; int bi = 0;
    #pragma unroll
    for (int c=0;c<NCLS;c++){ float v = (e[c]/ssum)*obj; if (v > best){ best=v; bi=c; } }

    int xb = 63 + a*4;
    float tx = p[(size_t)(xb+0)*HW + hw];
    float ty = p[(size_t)(xb+1)*HW + hw];
    float tw = p[(size_t)(xb+2)*HW + hw];
    float th = p[(size_t)(xb+3)*HW + hw];
    float aw = c_aw[L*3+a], ah = c_ah[L*3+a];
    if (hw == HW-1){ aw=0.f; ah=0.f; }          // ref quirk: awh[hs*ws-1]=0 per level
    float cx = sig(tx) + (float)w;
    float cy = sig(ty) + (float)h;
    float bw = expf(tw)*aw, bh = expf(th)*ah;
    float hx = bw*0.5f,  hy = bh*0.5f;
    float x1 = ((cx-hx)*s)/416.0f;
    float y1 = ((cy-hy)*s)/416.0f;
    float x2 = ((cx+hx)*s)/416.0f;
    float y2 = ((cy+hy)*s)/416.0f;

    out[n*4+0] = fminf(fmaxf(x1*416.0f,0.f),415.f)/416.0f;
    out[n*4+1] = fminf(fmaxf(y1*416.0f,0.f),415.f)/416.0f;
    out[n*4+2] = fminf(fmaxf(x2*416.0f,0.f),415.f)/416.0f;
    out[n*4+3] = fminf(fmaxf(y2*416.0f,0.f),415.f)/416.0f;
    out[OUT_SCORES + n] = best;
    out[OUT_CLS    + n] = (float)bi;

    box4[n]   = make_float4(x1,y1,x2,y2);
    // stable argsort(-scores): ascending by (~score_bits, idx). scores > 0 so bits are monotone.
    keys[n]   = ((u64)(~__float_as_uint(best)) << 32) | (u32)n;
    clsind[n] = bi;
    valid[n]  = (best >= 0.001f) ? 1 : 0;
}

// ---------------- Phase 2: bitonic sort of 16384 u64 keys, split in 8192-halves
__global__ __launch_bounds__(1024) void sort_half(const u64* __restrict__ keysIn,
                                                  u64* __restrict__ keysOut)
{
    __shared__ u64 lk[8192];                    // exactly 64 KB
    int b = blockIdx.x, tid = threadIdx.x;
    bool desc = (b == 1);                       // half0 asc, half1 desc -> bitonic 16384
    for (int t=tid;t<8192;t+=1024){ int g=b*8192+t; lk[t] = (g<NA)? keysIn[g] : ~0ull; }
    __syncthreads();
    for (int k=2;k<=8192;k<<=1){
        for (int j=k>>1;j>0;j>>=1){
            for (int t=tid;t<4096;t+=1024){
                int low=t&(j-1); int i=((t^low)<<1)|low; int ix=i|j;
                bool asc = ((i&k)==0) != desc;
                u64 A=lk[i], B=lk[ix];
                if ((A>B)==asc){ lk[i]=B; lk[ix]=A; }
            }
            __syncthreads();
        }
    }
    for (int t=tid;t<8192;t+=1024) keysOut[b*8192+t]=lk[t];
}

__global__ void merge_step(u64* __restrict__ keys){   // k=16384, j=8192 step, ascending
    int t = blockIdx.x*256 + threadIdx.x;
    if (t < 8192){ u64 A=keys[t], B=keys[t+8192]; if (A>B){ keys[t]=B; keys[t+8192]=A; } }
}

__global__ __launch_bounds__(1024) void sort_final(const u64* __restrict__ keys,
                                                   u32* __restrict__ order)
{
    __shared__ u64 lk[8192];
    int b=blockIdx.x, tid=threadIdx.x;
    for (int t=tid;t<8192;t+=1024) lk[t]=keys[b*8192+t];
    __syncthreads();
    for (int j=4096;j>0;j>>=1){                 // remaining merge steps, all ascending
        for (int t=tid;t<4096;t+=1024){
            int low=t&(j-1); int i=((t^low)<<1)|low; int ix=i|j;
            u64 A=lk[i], B=lk[ix];
            if (A>B){ lk[i]=B; lk[ix]=A; }
        }
        __syncthreads();
    }
    for (int t=tid;t<8192;t+=1024){ int g=b*8192+t; if (g<NA) order[g]=(u32)lk[t]; }
}

// ---------------- Phase 3: stable partition by class -------------------------
// Block b collects (in global sorted order) all boxes of class b.
__global__ __launch_bounds__(256) void partition_kernel(
    const u32* __restrict__ order, const float4* __restrict__ box4,
    const int* __restrict__ clsind, const unsigned char* __restrict__ valid,
    float4* __restrict__ cls_box, float* __restrict__ cls_area,
    u32* __restrict__ cls_orig, unsigned char* __restrict__ cls_val,
    int* __restrict__ cls_cnt)
{
    int b = blockIdx.x;
    int tid = threadIdx.x, wv = tid>>6, ln = tid&63;
    __shared__ int wcnt[4];
    int cnt = 0;
    for (int base = 0; base < NA; base += 256){
        int i = base + tid;
        bool take = false; u32 o = 0;
        if (i < NA){ o = order[i]; take = (clsind[o] == b); }
        u64 m = __ballot(take);
        int pre = __popcll(m & ((1ull<<ln)-1ull));
        if (ln == 0) wcnt[wv] = __popcll(m);
        __syncthreads();
        int woff = 0;
        #pragma unroll
        for (int w=0; w<4; w++) if (w < wv) woff += wcnt[w];
        int tot = wcnt[0]+wcnt[1]+wcnt[2]+wcnt[3];
        if (take){
            int pos = cnt + woff + pre;
            if (pos < CAP){
                float4 bx = box4[o];
                cls_box[b*CAP+pos]  = bx;
                cls_area[b*CAP+pos] = (bx.z-bx.x)*(bx.w-bx.y);
                cls_orig[b*CAP+pos] = o;
                cls_val[b*CAP+pos]  = valid[o];
            }
        }
        cnt += tot;
        __syncthreads();
    }
    if (tid == 0) cls_cnt[b] = (cnt < CAP) ? cnt : CAP;
}

// ---------------- Phase 4: per-class NMS entirely in LDS ---------------------
// One block per class. Wave 0 resolves each 64-chunk serially; diagonal block
// held as per-lane COLUMN words so "row bp's word" = ballot of bit bp.
// All 4 waves do the forward suppression (IoU on the fly, LDS-resident boxes).
__global__ __launch_bounds__(256) void nms_kernel(
    const float4* __restrict__ cls_box, const float* __restrict__ cls_area,
    const u32* __restrict__ cls_orig, const unsigned char* __restrict__ cls_val,
    const int* __restrict__ cls_cnt, float* __restrict__ keep_out)
{
    int b = blockIdx.x;
    int tid = threadIdx.x, wv = tid>>6, ln = tid&63;
    __shared__ float4 lbox[CAP];          // 32 KB
    __shared__ float  larea[CAP];         //  8 KB
    __shared__ u64 validw[CAP/64];
    __shared__ u64 remw[CAP/64];
    __shared__ u64 keepw_s[CAP/64];
    __shared__ u64 keep_bc;

    int M = cls_cnt[b];
    if (M > CAP) M = CAP;
    const float4* gB = cls_box  + (size_t)b*CAP;
    const float*  gA = cls_area + (size_t)b*CAP;
    const unsigned char* gV = cls_val + (size_t)b*CAP;

    int MC = (M + 63) & ~63;              // padded to chunk
    for (int t = tid; t < MC; t += 256){
        lbox[t]  = (t < M) ? gB[t] : make_float4(0.f,0.f,0.f,0.f);
        larea[t] = (t < M) ? gA[t] : 0.f;
    }
    int nw = MC >> 6;
    for (int w = tid; w < nw; w += 256) remw[w] = 0ull;
    for (int w0 = wv; w0 < nw; w0 += 4){
        int t = w0*64 + ln;
        u64 bm = __ballot(t < M && gV[t]);
        if (ln == 0) validw[w0] = bm;
    }
    __syncthreads();

    for (int c = 0; c < nw; c++){
        if (wv == 0){
            // diagonal 64x64 block, column layout: colw bit i = iou(row i, col ln) > 0.5
            int col = c*64 + ln;
            float4 cb = lbox[col]; float ca = larea[col];
            u64 colw = 0;
            for (int i = 0; i < 64; i++){
                float4 rb = lbox[c*64+i]; float ra = larea[c*64+i];   // LDS broadcast
                float xx1=fmaxf(rb.x,cb.x), yy1=fmaxf(rb.y,cb.y);
                float xx2=fminf(rb.z,cb.z), yy2=fminf(rb.w,cb.w);
                float inter=fmaxf(1e-28f,xx2-xx1)*fmaxf(1e-28f,yy2-yy1);
                float iou = inter/((ra+ca)-inter);
                colw |= (u64)(iou > 0.5f) << i;
            }
            u64 rem  = remw[c];
            u64 cand = validw[c] & ~rem;
            u64 keepw = 0;
            while (cand){                              // uniform (cand same in all lanes)
                int bp = __builtin_ctzll(cand);
                u64 rowm = __ballot((colw >> bp) & 1ull);   // row bp's word
                keepw |= 1ull << bp;
                cand &= ~(rowm | (1ull << bp));
            }
            if (ln == 0){ keepw_s[c] = keepw; keep_bc = keepw; }
        }
        __syncthreads();
        u64 kk = keep_bc;
        int fbase = (c+1)*64;
        if (fbase < MC){
            while (kk){                                // uniform across block
                int bp = __builtin_ctzll(kk); kk &= kk - 1;
                float4 rb = lbox[c*64+bp]; float ra = larea[c*64+bp];
                for (int j = fbase + tid; j < MC; j += 256){
                    bool pred = false;
                    if (j < M){
                        float4 cb2 = lbox[j];
                        float xx1=fmaxf(rb.x,cb2.x), yy1=fmaxf(rb.y,cb2.y);
                        float xx2=fminf(rb.z,cb2.z), yy2=fminf(rb.w,cb2.w);
                        float inter=fmaxf(1e-28f,xx2-xx1)*fmaxf(1e-28f,yy2-yy1);
                        float iou = inter/((ra+larea[j])-inter);
                        pred = iou > 0.5f;
                    }
                    u64 bm = __ballot(pred);           // j 64-aligned per wave
                    if (ln == 0 && bm) atomicOr(&remw[j>>6], bm);
                }
            }
        }
        __syncthreads();
    }

    for (int m = tid; m < M; m += 256){
        keep_out[cls_orig[(size_t)b*CAP + m]] =
            ((keepw_s[m>>6] >> (m&63)) & 1ull) ? 1.0f : 0.0f;
    }
}

// ---------------- launch -----------------------------------------------------
extern "C" void kernel_launch(void* const* d_in, const int* in_sizes, int n_in,
                              void* d_out, int out_size, void* d_ws, size_t ws_size,
                              hipStream_t stream) {
    const float* p1 = (const float*)d_in[0];
    const float* p2 = (const float*)d_in[1];
    const float* p3 = (const float*)d_in[2];
    float* out = (float*)d_out;

    char* ws = (char*)d_ws;
    size_t off = 0;
    auto alloc = [&](size_t bytes)->void*{ void* p = ws + off; off += (bytes + 255) & ~(size_t)255; return p; };
    float4* box4          = (float4*)alloc((size_t)NA*16);
    u64*    keys          = (u64*)   alloc((size_t)SORT_N*8);
    int*    clsind        = (int*)   alloc((size_t)NA*4);
    unsigned char* valid  = (unsigned char*)alloc(NA);
    u32*    order         = (u32*)   alloc((size_t)NA*4);
    float4* cls_box       = (float4*)alloc((size_t)NCLS*CAP*16);
    float*  cls_area      = (float*) alloc((size_t)NCLS*CAP*4);
    u32*    cls_orig      = (u32*)   alloc((size_t)NCLS*CAP*4);
    unsigned char* cls_val= (unsigned char*)alloc((size_t)NCLS*CAP);
    int*    cls_cnt       = (int*)   alloc((size_t)NCLS*4);

    decode_kernel<<<(NA+255)/256, 256, 0, stream>>>(p1,p2,p3,out,box4,keys,clsind,valid);
    sort_half   <<<2, 1024, 0, stream>>>(keys, keys);
    merge_step  <<<32, 256, 0, stream>>>(keys);
    sort_final  <<<2, 1024, 0, stream>>>(keys, order);
    partition_kernel<<<NCLS, 256, 0, stream>>>(order, box4, clsind, valid,
                                               cls_box, cls_area, cls_orig, cls_val, cls_cnt);
    nms_kernel  <<<NCLS, 256, 0, stream>>>(cls_box, cls_area, cls_orig, cls_val,
                                           cls_cnt, out + OUT_KEEP);
}

// Round 4
// 221.424 us; speedup vs baseline: 11.3844x; 2.1869x over previous
//
#include <hip/hip_runtime.h>
#include <stdint.h>

typedef unsigned long long u64;
typedef unsigned int u32;

#define NA 10647            // total anchors: (52*52 + 26*26 + 13*13) * 3
#define NCLS 20
#define CAP 2048            // per-class capacity (mean 532, huge headroom)
#define OUT_SCORES 42588    // NA*4
#define OUT_CLS    53235    // NA*5
#define OUT_KEEP   63882    // NA*6

// anchors[level][a] * scale{4,2,1}
__constant__ float c_aw[9] = {4.f,8.f,12.f, 3.f,6.f,8.f, 3.5f,5.f,8.f};
__constant__ float c_ah[9] = {6.f,12.f,10.f, 7.f,8.f,6.f, 5.f,4.5f,8.f};

__device__ __forceinline__ float sig(float x){ return 1.0f/(1.0f+expf(-x)); }

// ---------------- Phase 1: decode (only batch 0 is used by the reference) ----
__global__ void decode_kernel(const float* __restrict__ p1, const float* __restrict__ p2,
                              const float* __restrict__ p3, float* __restrict__ out,
                              float4* __restrict__ box4, u32* __restrict__ skey,
                              int* __restrict__ clsind, unsigned char* __restrict__ valid)
{
    int n = blockIdx.x*256 + threadIdx.x;
    if (n >= NA) return;
    const float* p; int base, W, HW, L; float s;
    if (n < 8112)      { p=p1; base=0;     W=52; HW=2704; s=8.f;  L=0; }
    else if (n<10140)  { p=p2; base=8112;  W=26; HW=676;  s=16.f; L=1; }
    else               { p=p3; base=10140; W=13; HW=169;  s=32.f; L=2; }
    int r  = n - base;
    int hw = r/3, a = r - hw*3;
    int h  = hw/W, w = hw - h*W;

    // layout: pred[0, ch, h, w] = p[ch*HW + hw];  obj=ch a, cls=ch 3+a*20+c, xywh=ch 63+a*4+j
    float obj = sig(p[(size_t)a*HW + hw]);

    float e[NCLS];
    #pragma unroll
    for (int c=0;c<NCLS;c++) e[c] = p[(size_t)(3 + a*NCLS + c)*HW + hw];
    float xmax = e[0];
    #pragma unroll
    for (int c=1;c<NCLS;c++) xmax = fmaxf(xmax, e[c]);
    float ssum = 0.f;
    #pragma unroll
    for (int c=0;c<NCLS;c++){ e[c] = expf(e[c]-xmax); ssum += e[c]; }
    // mirror ref: all_class = (exp/sum)*obj, argmax first-max, score = max
    float best = -1.0f; int bi = 0;
    #pragma unroll
    for (int c=0;c<NCLS;c++){ float v = (e[c]/ssum)*obj; if (v > best){ best=v; bi=c; } }

    int xb = 63 + a*4;
    float tx = p[(size_t)(xb+0)*HW + hw];
    float ty = p[(size_t)(xb+1)*HW + hw];
    float tw = p[(size_t)(xb+2)*HW + hw];
    float th = p[(size_t)(xb+3)*HW + hw];
    float aw = c_aw[L*3+a], ah = c_ah[L*3+a];
    if (hw == HW-1){ aw=0.f; ah=0.f; }          // ref quirk: awh[hs*ws-1]=0 per level
    float cx = sig(tx) + (float)w;
    float cy = sig(ty) + (float)h;
    float bw = expf(tw)*aw, bh = expf(th)*ah;
    float hx = bw*0.5f,  hy = bh*0.5f;
    float x1 = ((cx-hx)*s)/416.0f;
    float y1 = ((cy-hy)*s)/416.0f;
    float x2 = ((cx+hx)*s)/416.0f;
    float y2 = ((cy+hy)*s)/416.0f;

    out[n*4+0] = fminf(fmaxf(x1*416.0f,0.f),415.f)/416.0f;
    out[n*4+1] = fminf(fmaxf(y1*416.0f,0.f),415.f)/416.0f;
    out[n*4+2] = fminf(fmaxf(x2*416.0f,0.f),415.f)/416.0f;
    out[n*4+3] = fminf(fmaxf(y2*416.0f,0.f),415.f)/416.0f;
    out[OUT_SCORES + n] = best;
    out[OUT_CLS    + n] = (float)bi;

    box4[n]   = make_float4(x1,y1,x2,y2);
    // stable argsort(-scores): ascending by (~score_bits, idx). scores > 0 so bits monotone.
    skey[n]   = ~__float_as_uint(best);
    clsind[n] = bi;
    valid[n]  = (best >= 0.001f) ? 1 : 0;
}

// ---------------- Phase 2: fused per-class gather + sort + NMS ---------------
// One block per class (20 blocks x 512 threads). Everything after the gather
// runs out of LDS: bitonic sort of (key,idx), then chunked greedy NMS with
// parallel diagonal build and column-parallel forward suppression.
__global__ __launch_bounds__(512) void nms_all(
    const float4* __restrict__ box4, const u32* __restrict__ skey,
    const int* __restrict__ clsind, const unsigned char* __restrict__ valid,
    float* __restrict__ keep_out)
{
    int b = blockIdx.x;
    int tid = threadIdx.x, wv = tid>>6, ln = tid&63;
    __shared__ u64    lkey[CAP];          // 16 KB
    __shared__ float4 lbox[CAP];          // 32 KB
    __shared__ float  larea[CAP];         //  8 KB
    __shared__ u64 validw[CAP/64];
    __shared__ u64 remw[CAP/64];
    __shared__ u64 keepw_s[CAP/64];
    __shared__ u64 diag_p[8][64];         //  4 KB
    __shared__ int wcnt[8];
    __shared__ u64 keep_bc;

    // ---- gather: class-b boxes in original-index order (order irrelevant; key sorts) ----
    int cnt = 0;
    for (int base = 0; base < NA; base += 512){
        int i = base + tid;
        bool take = (i < NA) && (clsind[i] == b);
        u64 m = __ballot(take);
        if (ln == 0) wcnt[wv] = __popcll(m);
        __syncthreads();
        int pre = __popcll(m & ((1ull<<ln)-1ull));
        int woff = 0, tot = 0;
        #pragma unroll
        for (int w=0; w<8; w++){ int cc = wcnt[w]; if (w < wv) woff += cc; tot += cc; }
        if (take){
            int pos = cnt + woff + pre;
            if (pos < CAP) lkey[pos] = ((u64)skey[i] << 32) | (u32)i;
            else keep_out[i] = 0.0f;      // unreachable overflow guard: no poison leak
        }
        cnt += tot;
        __syncthreads();
    }
    int M = (cnt < CAP) ? cnt : CAP;

    // ---- bitonic sort lkey[0..P), P = next pow2 >= M ----
    int P = 64; while (P < M) P <<= 1;
    for (int t = tid; t < P; t += 512) if (t >= M) lkey[t] = ~0ull;
    __syncthreads();
    for (int k = 2; k <= P; k <<= 1){
        for (int j = k >> 1; j > 0; j >>= 1){
            for (int t = tid; t < (P>>1); t += 512){
                int low = t & (j-1); int i1 = ((t ^ low) << 1) | low; int i2 = i1 | j;
                bool asc = (i1 & k) == 0;
                u64 A = lkey[i1], B = lkey[i2];
                if ((A > B) == asc){ lkey[i1] = B; lkey[i2] = A; }
            }
            __syncthreads();
        }
    }

    // ---- fetch boxes into sorted LDS slots ----
    int MC = (M + 63) & ~63;
    int nw = MC >> 6;
    for (int t = tid; t < MC; t += 512){           // MC mult of 64 -> wave-granular
        float4 bx = make_float4(0.f,0.f,0.f,0.f);
        bool v = false;
        if (t < M){ u32 o = (u32)lkey[t]; bx = box4[o]; v = (valid[o] != 0); }
        lbox[t] = bx;
        larea[t] = (bx.z-bx.x)*(bx.w-bx.y);
        u64 bm = __ballot(v);                       // (t&63)==ln, word-aligned per wave
        if (ln == 0) validw[t>>6] = bm;
    }
    for (int w = tid; w < nw; w += 512) remw[w] = 0ull;
    __syncthreads();

    // ---- chunked greedy NMS ----
    for (int c = 0; c < nw; c++){
        // 1) diagonal 64x64 IoU block, rows split across 8 waves, column = lane
        {
            float4 cb = lbox[c*64 + ln]; float ca = larea[c*64 + ln];
            u64 part = 0;
            #pragma unroll
            for (int r = 0; r < 8; r++){
                int i = 8*wv + r;
                float4 rb = lbox[c*64 + i]; float ra = larea[c*64 + i];
                float xx1=fmaxf(rb.x,cb.x), yy1=fmaxf(rb.y,cb.y);
                float xx2=fminf(rb.z,cb.z), yy2=fminf(rb.w,cb.w);
                float inter=fmaxf(1e-28f,xx2-xx1)*fmaxf(1e-28f,yy2-yy1);
                float iou = inter/((ra+ca)-inter);
                part |= (u64)(iou > 0.5f) << i;
            }
            diag_p[wv][ln] = part;
        }
        __syncthreads();
        // 2) serial greedy resolve of this chunk (wave 0), column-word + ballot trick
        if (wv == 0){
            u64 colw = diag_p[0][ln]|diag_p[1][ln]|diag_p[2][ln]|diag_p[3][ln]
                      |diag_p[4][ln]|diag_p[5][ln]|diag_p[6][ln]|diag_p[7][ln];
            u64 rem  = remw[c];
            u64 cand = validw[c] & ~rem;
            u64 keepw = 0;
            while (cand){                          // uniform (cand same in all lanes)
                int bp = __builtin_ctzll(cand);
                u64 rowm = __ballot((colw >> bp) & 1ull);   // row bp's in-chunk word
                keepw |= 1ull << bp;
                cand &= ~(rowm | (1ull << bp));
            }
            if (ln == 0){ keepw_s[c] = keepw; keep_bc = keepw; }
        }
        __syncthreads();
        u64 kk = keep_bc;
        // 3) forward suppression, column-parallel: thread owns column j, loops rows
        if (kk){
            for (int j = (c+1)*64 + tid; j < MC; j += 512){
                float4 cb = lbox[j]; float ca = larea[j];
                bool s = false;
                #pragma unroll 8
                for (int i = 0; i < 64; i++){
                    if ((kk >> i) & 1ull){          // uniform branch (kk is wave-uniform)
                        float4 rb = lbox[c*64 + i]; float ra = larea[c*64 + i];
                        float xx1=fmaxf(rb.x,cb.x), yy1=fmaxf(rb.y,cb.y);
                        float xx2=fminf(rb.z,cb.z), yy2=fminf(rb.w,cb.w);
                        float inter=fmaxf(1e-28f,xx2-xx1)*fmaxf(1e-28f,yy2-yy1);
                        float iou = inter/((ra+ca)-inter);
                        s |= (iou > 0.5f);
                    }
                }
                u64 bm = __ballot(s);               // j word-aligned per wave
                if (ln == 0 && bm) atomicOr(&remw[j>>6], bm);
            }
        }
        __syncthreads();
    }

    // ---- write keep bits back to original indices ----
    for (int t = tid; t < M; t += 512){
        keep_out[(u32)lkey[t]] = ((keepw_s[t>>6] >> (t&63)) & 1ull) ? 1.0f : 0.0f;
    }
}

// ---------------- launch -----------------------------------------------------
extern "C" void kernel_launch(void* const* d_in, const int* in_sizes, int n_in,
                              void* d_out, int out_size, void* d_ws, size_t ws_size,
                              hipStream_t stream) {
    const float* p1 = (const float*)d_in[0];
    const float* p2 = (const float*)d_in[1];
    const float* p3 = (const float*)d_in[2];
    float* out = (float*)d_out;

    char* ws = (char*)d_ws;
    size_t off = 0;
    auto alloc = [&](size_t bytes)->void*{ void* p = ws + off; off += (bytes + 255) & ~(size_t)255; return p; };
    float4* box4          = (float4*)alloc((size_t)NA*16);
    u32*    skey          = (u32*)   alloc((size_t)NA*4);
    int*    clsind        = (int*)   alloc((size_t)NA*4);
    unsigned char* valid  = (unsigned char*)alloc(NA);

    decode_kernel<<<(NA+255)/256, 256, 0, stream>>>(p1,p2,p3,out,box4,skey,clsind,valid);
    nms_all     <<<NCLS, 512, 0, stream>>>(box4, skey, clsind, valid, out + OUT_KEEP);
}